// Round 9
// baseline (620.231 us; speedup 1.0000x reference)
//
#include <hip/hip_runtime.h>
#include <hip/hip_bf16.h>
#include <cstdio>

namespace {

constexpr int kSeq = 2048;
constexpr int kDModel = 2048;
constexpr int kHeads = 16;
constexpr int kDk = 128;
constexpr int kBatch = 2;
constexpr int kM = kBatch * kSeq;  // 4096 rows of x
constexpr float kQScale = 0.08838834764831845f;  // 1/sqrt(128)

typedef __bf16 bf16_t;
typedef __bf16 bf16x8 __attribute__((ext_vector_type(8)));
typedef __bf16 bf16x4 __attribute__((ext_vector_type(4)));
typedef float f32x4 __attribute__((ext_vector_type(4)));
typedef short s16x4 __attribute__((ext_vector_type(4)));

__device__ __forceinline__ f32x4 mfma32(bf16x8 a, bf16x8 b, f32x4 c) {
  return __builtin_amdgcn_mfma_f32_16x16x32_bf16(a, b, c, 0, 0, 0);
}

#if __has_builtin(__builtin_amdgcn_mfma_f32_16x16x16_bf16)
__device__ __forceinline__ f32x4 mfma16(bf16x4 a, bf16x4 b, f32x4 c) {
  return __builtin_amdgcn_mfma_f32_16x16x16_bf16(a, b, c, 0, 0, 0);
}
#else
__device__ __forceinline__ f32x4 mfma16(bf16x4 a, bf16x4 b, f32x4 c) {
  union U { bf16x4 b; s16x4 s; } ua, ub;
  ua.b = a; ub.b = b;
  return __builtin_amdgcn_mfma_f32_16x16x16bf16_1k(ua.s, ub.s, c, 0, 0, 0);
}
#endif

using gas_void = const __attribute__((address_space(1))) void;
using las_void = __attribute__((address_space(3))) void;

__device__ __forceinline__ void gload_lds16(const bf16_t* g, bf16_t* l) {
  __builtin_amdgcn_global_load_lds((gas_void*)g, (las_void*)l, 16, 0, 0);
}

// ---------------- RoPE table (fp64 for max fidelity vs np reference) --------
__global__ void k_rope_table(float* __restrict__ cost, float* __restrict__ sint) {
  const int p = blockIdx.x;
  const int i = threadIdx.x;
  const double inv = exp(-(double)(2 * i) * 9.210340371976184 / 128.0);
  const double ang = (double)p * inv;
  cost[p * 64 + i] = (float)cos(ang);
  sint[p * 64 + i] = (float)sin(ang);
}

// ---------------- x -> (hi,lo) bf16 split -----------------------------------
__global__ void k_split_x(const float* __restrict__ x, bf16_t* __restrict__ xh,
                          bf16_t* __restrict__ xl, int n) {
  const int idx = (blockIdx.x * blockDim.x + threadIdx.x) * 4;
  if (idx >= n) return;
  const float4 v = *(const float4*)(x + idx);
  const float vv[4] = {v.x, v.y, v.z, v.w};
  bf16x4 hv, lv;
#pragma unroll
  for (int j = 0; j < 4; ++j) {
    const bf16_t h = (bf16_t)vv[j];
    hv[j] = h;
    lv[j] = (bf16_t)(vv[j] - (float)h);
  }
  *(bf16x4*)(xh + idx) = hv;
  *(bf16x4*)(xl + idx) = lv;
}

// ---------------- W (fp32 [K][N]) -> W^T bf16 hi(/lo) [N][K] ----------------
__global__ void k_transpose_w(const float* __restrict__ w, bf16_t* __restrict__ wth,
                              bf16_t* __restrict__ wtl) {
  __shared__ float tile[32][33];
  const int bx = blockIdx.x * 32;  // n
  const int by = blockIdx.y * 32;  // k
  const int tx = threadIdx.x, ty = threadIdx.y;
#pragma unroll
  for (int i = 0; i < 32; i += 8)
    tile[ty + i][tx] = w[(size_t)(by + ty + i) * kDModel + bx + tx];
  __syncthreads();
#pragma unroll
  for (int i = 0; i < 32; i += 8) {
    const float v = tile[tx][ty + i];
    const size_t o = (size_t)(bx + ty + i) * kDModel + by + tx;
    const bf16_t h = (bf16_t)v;
    wth[o] = h;
    if (wtl) wtl[o] = (bf16_t)(v - (float)h);
  }
}

// ---------------- Fused Q|K projection: 4-wave, 2 blocks/CU TLP -------------
// 256 threads (2M x 2N waves), tile BM=256 x BN=128, wave-tile 128x64
// (acc[8][4]); BK=32. Reads/MFMA = 12/32 (0.375, vs 0.5 at 64x64 tiles).
// LDS ring-2 = 2 x (A 16KB + B 8KB) = 48KB -> 2 blocks/CU co-resident
// (grid 512 = 2/CU): cross-block TLP hides the per-tile vmcnt drain (m114
// mechanism) -- no manual waitcnt/setprio (every hand-pin regressed r6-r8).
// Swizzle (64B rows, 4 chunks): pos = chunk ^ ((row>>1)&3), both sides
// (r8-verified: 0 bank conflicts).
// Ledger: STAGE(t+1)->slot (t+1)&1 issued before compute(t) reads slot t&1;
// barrier at iter end drains vmcnt (compiler) -> t+1 landed, readers of
// slot (t+1)&1 (iter t-1) all passed barrier before the stage issued.
// Segmented K' = [Ah,Ah,Al] x [Bh,Bl,Bh] (split-bf16 ~fp32), 192 tiles.
__global__ __launch_bounds__(256, 2) void k_gemmqk2(
    const bf16_t* __restrict__ Ah, const bf16_t* __restrict__ Al,
    const bf16_t* __restrict__ Bh, const bf16_t* __restrict__ Bl,
    bf16_t* __restrict__ Qh, bf16_t* __restrict__ Ql,
    bf16_t* __restrict__ Kh, bf16_t* __restrict__ Kl,
    const int* __restrict__ tokpos, const float* __restrict__ cost,
    const float* __restrict__ sint) {
  __shared__ __align__(16) bf16_t sA[2][256 * 32];
  __shared__ __align__(16) bf16_t sB[2][128 * 32];
  constexpr int ntk = 192;

  const int tid = threadIdx.x;
  const int wid = tid >> 6, lane = tid & 63;
  const int lo = lane & 15, hi = lane >> 4;
  const int wr = wid >> 1, wc = wid & 1;

  const int bid = blockIdx.x;  // 512 blocks = 2/CU
  const int wgid = (bid & 7) * 64 + (bid >> 3);  // bijective XCD swizzle
  const int mt = wgid >> 5, nt = wgid & 31;
  const int m0 = mt * 256, n0 = nt * 128;

  // ---- staging source constants (pre-swizzled: chunk ^ ((row>>1)&3)) ----
  const int sr = tid >> 2;                           // row 0..63 per issue
  const int sc = ((tid & 3) ^ ((sr >> 1) & 3)) * 8;  // swizzled chunk (elems)
  size_t offA[4];
#pragma unroll
  for (int ui = 0; ui < 4; ++ui)
    offA[ui] = (size_t)(m0 + ui * 64 + sr) * 2048 + sc;
  size_t offB[2];
#pragma unroll
  for (int i = 0; i < 2; ++i)
    offB[i] = (size_t)(n0 + i * 64 + sr) * 2048 + sc;

  auto STAGE = [&](int slot, int tt) {
    const bf16_t *As, *Bs;
    if (tt < 64) {
      As = Ah; Bs = Bh;
    } else if (tt < 128) {
      As = Ah; Bs = Bl;
    } else {
      As = Al; Bs = Bh;
    }
    const int kb = (tt & 63) * 32;
#pragma unroll
    for (int ui = 0; ui < 4; ++ui)
      gload_lds16(As + offA[ui] + kb, sA[slot] + ui * 2048 + tid * 8);
#pragma unroll
    for (int i = 0; i < 2; ++i)
      gload_lds16(Bs + offB[i] + kb, sB[slot] + i * 2048 + tid * 8);
  };

  // ---- fragment LDS offsets (row*32 + swizzled chunk*8) ----
  const int xq = (lo >> 1) & 3;  // == (row>>1)&3 for row = 16*k + lo
  int aoff[8], boff[4];
#pragma unroll
  for (int mi = 0; mi < 8; ++mi)
    aoff[mi] = (wr * 128 + mi * 16 + lo) * 32 + ((hi ^ xq) * 8);
#pragma unroll
  for (int ni = 0; ni < 4; ++ni)
    boff[ni] = (wc * 64 + ni * 16 + lo) * 32 + ((hi ^ xq) * 8);

  f32x4 acc[8][4];
  const f32x4 z = {0.f, 0.f, 0.f, 0.f};
#pragma unroll
  for (int i = 0; i < 8; ++i)
#pragma unroll
    for (int j = 0; j < 4; ++j) acc[i][j] = z;

  STAGE(0, 0);
  __syncthreads();

#pragma unroll 1
  for (int t = 0; t < ntk; ++t) {
    if (t + 1 < ntk) STAGE((t + 1) & 1, t + 1);
    const bf16_t* sa = sA[t & 1];
    const bf16_t* sb = sB[t & 1];
    bf16x8 af[8], bfr[4];
#pragma unroll
    for (int mi = 0; mi < 8; ++mi) af[mi] = *(const bf16x8*)(sa + aoff[mi]);
#pragma unroll
    for (int ni = 0; ni < 4; ++ni) bfr[ni] = *(const bf16x8*)(sb + boff[ni]);
#pragma unroll
    for (int ni = 0; ni < 4; ++ni)
#pragma unroll
      for (int mi = 0; mi < 8; ++mi)
        acc[mi][ni] = mfma32(af[mi], bfr[ni], acc[mi][ni]);
    __syncthreads();  // drains vmcnt: tile t+1 landed; slot reuse safe
  }

  // ---- epilogue: RoPE + split-bf16 store; block-uniform Q/K select ----
  const int qk = n0 >> 11;  // 0 = Q (cols<2048), 1 = K
  bf16_t* Xh = qk ? Kh : Qh;
  bf16_t* Xl = qk ? Kl : Ql;
  const float scale = qk ? 1.0f : kQScale;
  const int is64 = (tokpos[1] == 0) ? 1 : 0;
#pragma unroll
  for (int mi = 0; mi < 8; ++mi) {
#pragma unroll
    for (int r = 0; r < 4; ++r) {
      const int row = m0 + wr * 128 + mi * 16 + hi * 4 + r;
      const int pos = is64 ? tokpos[2 * row] : tokpos[row];
#pragma unroll
      for (int ni = 0; ni < 4; ++ni) {
        const int col = n0 + wc * 64 + ni * 16 + lo;
        const float v = acc[mi][ni][r] * scale;
        const float pv = __shfl_xor(v, 1);  // paired column (col^1)
        const int ip = (col & 127) >> 1;
        const float c = cost[pos * 64 + ip];
        const float sn = sint[pos * 64 + ip];
        const float sgn = (lo & 1) ? sn : -sn;
        const float rv = v * c + pv * sgn;
        const bf16_t hb = (bf16_t)rv;
        const size_t o = (size_t)row * 2048 + (col & 2047);
        Xh[o] = hb;
        Xl[o] = (bf16_t)(rv - (float)hb);
      }
    }
  }
}

// ---------------- Ring-3 counted-vmcnt MFMA GEMM (V / O projections) --------
// BM=256, BN=128, BK=64. 8 waves (4Mx2N), wave C = 64x64 (acc[4][4]).
// EPI: 0 = fp32 store; 2 = bf16 V^T store [bh*128+d][s].
template <int EPI>
__global__ __launch_bounds__(512) void k_gemm8(
    const bf16_t* __restrict__ Ah, const bf16_t* __restrict__ Bh,
    void* __restrict__ O0, int NT, int ntk) {
  __shared__ __align__(16) bf16_t sA[3][256 * 64];
  __shared__ __align__(16) bf16_t sB[3][128 * 64];

  const int tid = threadIdx.x;
  const int wid = tid >> 6, lane = tid & 63;
  const int lo = lane & 15, hi = lane >> 4;
  const int wrr = wid >> 1, wcc = wid & 1;
  const int x7 = lo & 7;

  const int bid = blockIdx.x;
  const int wgid = (bid & 7) * (gridDim.x >> 3) + (bid >> 3);
  const int mt = wgid / NT, nt = wgid % NT;
  const int m0 = mt * 256, n0 = nt * 128;

  const int rB = tid >> 3;
  const int ch8 = ((tid & 7) ^ (rB & 7)) * 8;
  size_t offA[4], offB[2];
#pragma unroll
  for (int u = 0; u < 2; ++u)
#pragma unroll
    for (int i = 0; i < 2; ++i)
      offA[u * 2 + i] = (size_t)(m0 + u * 128 + i * 64 + rB) * 2048 + ch8;
#pragma unroll
  for (int i = 0; i < 2; ++i)
    offB[i] = (size_t)(n0 + i * 64 + rB) * 2048 + ch8;
  const int ldsOff = wid * 512;

  auto STAGE_A = [&](int slot, int t) {
    const bf16_t* base = Ah + t * 64;
    bf16_t* d = sA[slot] + ldsOff;
#pragma unroll
    for (int ui = 0; ui < 4; ++ui) gload_lds16(base + offA[ui], d + ui * 4096);
  };
  auto STAGE_B = [&](int slot, int t) {
    const bf16_t* base = Bh + t * 64;
    bf16_t* d = sB[slot] + ldsOff;
#pragma unroll
    for (int i = 0; i < 2; ++i) gload_lds16(base + offB[i], d + i * 4096);
  };

  int aoff[4][2], boff[4][2];
#pragma unroll
  for (int mi = 0; mi < 4; ++mi)
#pragma unroll
    for (int ks = 0; ks < 2; ++ks)
      aoff[mi][ks] = (wrr * 64 + mi * 16 + lo) * 64 + (((ks * 4 + hi) ^ x7) * 8);
#pragma unroll
  for (int ni = 0; ni < 4; ++ni)
#pragma unroll
    for (int ks = 0; ks < 2; ++ks)
      boff[ni][ks] = (wcc * 64 + ni * 16 + lo) * 64 + (((ks * 4 + hi) ^ x7) * 8);

  f32x4 acc[4][4];
  const f32x4 z = {0.f, 0.f, 0.f, 0.f};
#pragma unroll
  for (int i = 0; i < 4; ++i)
#pragma unroll
    for (int j = 0; j < 4; ++j) acc[i][j] = z;

  STAGE_A(0, 0);
  STAGE_B(0, 0);
  STAGE_A(1, 1);
  STAGE_B(1, 1);
  asm volatile("s_waitcnt vmcnt(6)" ::: "memory");
  __builtin_amdgcn_s_barrier();
  asm volatile("" ::: "memory");

  int s0 = 0;
  for (int t = 0; t < ntk; ++t) {
    const bf16_t* sa = sA[s0];
    const bf16_t* sb = sB[s0];
    int s2 = s0 + 2;
    if (s2 >= 3) s2 -= 3;
    const bool pf = (t + 2 < ntk);

    bf16x8 af[2][2], bfr[4][2];
#pragma unroll
    for (int mi = 0; mi < 2; ++mi)
#pragma unroll
      for (int ks = 0; ks < 2; ++ks)
        af[mi][ks] = *(const bf16x8*)(sa + aoff[mi][ks]);
#pragma unroll
    for (int ni = 0; ni < 4; ++ni)
#pragma unroll
      for (int ks = 0; ks < 2; ++ks)
        bfr[ni][ks] = *(const bf16x8*)(sb + boff[ni][ks]);
    if (pf) STAGE_A(s2, t + 2);
    asm volatile("" ::: "memory");
    __builtin_amdgcn_s_barrier();
    asm volatile("" ::: "memory");
    __builtin_amdgcn_s_setprio(1);
#pragma unroll
    for (int ni = 0; ni < 4; ++ni)
#pragma unroll
      for (int mi = 0; mi < 2; ++mi)
#pragma unroll
        for (int ks = 0; ks < 2; ++ks)
          acc[mi][ni] = mfma32(af[mi][ks], bfr[ni][ks], acc[mi][ni]);
    __builtin_amdgcn_s_setprio(0);

    bf16x8 ag[2][2];
#pragma unroll
    for (int mi = 0; mi < 2; ++mi)
#pragma unroll
      for (int ks = 0; ks < 2; ++ks)
        ag[mi][ks] = *(const bf16x8*)(sa + aoff[2 + mi][ks]);
    if (pf) STAGE_B(s2, t + 2);
    if (pf)
      asm volatile("s_waitcnt vmcnt(6)" ::: "memory");
    else
      asm volatile("s_waitcnt vmcnt(0)" ::: "memory");
    __builtin_amdgcn_s_barrier();
    asm volatile("" ::: "memory");
    __builtin_amdgcn_s_setprio(1);
#pragma unroll
    for (int ni = 0; ni < 4; ++ni)
#pragma unroll
      for (int mi = 0; mi < 2; ++mi)
#pragma unroll
        for (int ks = 0; ks < 2; ++ks)
          acc[2 + mi][ni] = mfma32(ag[mi][ks], bfr[ni][ks], acc[2 + mi][ni]);
    __builtin_amdgcn_s_setprio(0);

    s0 += 1;
    if (s0 >= 3) s0 = 0;
  }

  if constexpr (EPI == 0) {
    float* C = (float*)O0;
#pragma unroll
    for (int mi = 0; mi < 4; ++mi)
#pragma unroll
      for (int ni = 0; ni < 4; ++ni)
#pragma unroll
        for (int r = 0; r < 4; ++r) {
          const int row = m0 + wrr * 64 + mi * 16 + hi * 4 + r;
          const int col = n0 + wcc * 64 + ni * 16 + lo;
          C[(size_t)row * 2048 + col] = acc[mi][ni][r];
        }
  } else {  // EPI == 2 : V^T per head [bh*128+d][s]
    bf16_t* VT = (bf16_t*)O0;
#pragma unroll
    for (int mi = 0; mi < 4; ++mi)
#pragma unroll
      for (int ni = 0; ni < 4; ++ni) {
        const int col = n0 + wcc * 64 + ni * 16 + lo;
        const int h = col >> 7, d = col & 127;
        const int rowb = m0 + wrr * 64 + mi * 16 + hi * 4;
        const int b = rowb >> 11, s = rowb & (kSeq - 1);
        bf16x4 ov;
#pragma unroll
        for (int r = 0; r < 4; ++r) ov[r] = (bf16_t)acc[mi][ni][r];
        *(bf16x4*)(VT + ((size_t)((b * kHeads + h) * kDk + d)) * kSeq + s) = ov;
      }
  }
}

// ---------------- Causal flash attention, strip-paired, 8 waves -------------
__global__ __launch_bounds__(512, 2) void k_attn4(
    const bf16_t* __restrict__ Qh, const bf16_t* __restrict__ Ql,
    const bf16_t* __restrict__ Kh, const bf16_t* __restrict__ Kl,
    const bf16_t* __restrict__ VT, bf16_t* __restrict__ Ob) {
  __shared__ __align__(16) bf16_t sK[2][2][64 * 128];
  __shared__ __align__(16) bf16_t sV[2][128 * 64];

  const int tid = threadIdx.x;
  const int wid = tid >> 6, lane = tid & 63;
  const int lo = lane & 15, hi = lane >> 4;
  const int flat = blockIdx.x;  // 256 blocks
  const int j = flat >> 3;
  const int bh = (flat & 7) * 4 + (j & 3);  // XCD x -> heads 4x..4x+3
  const int p = j >> 2;                     // 0..7
  const int b = bh >> 4, h = bh & 15;
  const int qiW = (wid < 4) ? (15 - p) : p;
  const int qw = qiW * 128 + (wid & 3) * 32;
  const int nkv = 2 * (15 - p) + 2;

  bf16x8 qhf[4][2], qlf[4][2];
  {
    const size_t qbase =
        (size_t)(b * kSeq + qw + lo) * kDModel + h * kDk + hi * 8;
#pragma unroll
    for (int qt = 0; qt < 2; ++qt)
#pragma unroll
      for (int ks = 0; ks < 4; ++ks) {
        const size_t o = qbase + (size_t)qt * 16 * kDModel + ks * 32;
        qhf[ks][qt] = *(const bf16x8*)(Qh + o);
        qlf[ks][qt] = *(const bf16x8*)(Ql + o);
      }
  }

  const int rK0 = wid * 8 + (lane >> 4);
  const int gK0 = ((lane & 15) ^ (rK0 & 15)) * 8;
  const int gK1 = ((lane & 15) ^ ((rK0 + 4) & 15)) * 8;
  const bf16_t* pKh0 = Kh + (size_t)(b * kSeq + rK0) * kDModel + h * kDk + gK0;
  const bf16_t* pKh1 = Kh + (size_t)(b * kSeq + rK0 + 4) * kDModel + h * kDk + gK1;
  const bf16_t* pKl0 = Kl + (pKh0 - Kh);
  const bf16_t* pKl1 = Kl + (pKh1 - Kh);
  const int dV0 = wid * 16 + (lane >> 3);
  const int gV0 = ((lane & 7) ^ (dV0 & 7)) * 8;
  const int gV1 = ((lane & 7) ^ ((dV0 + 8) & 7)) * 8;
  const bf16_t* pV0 = VT + (size_t)(bh * kDk + dV0) * kSeq + gV0;
  const bf16_t* pV1 = VT + (size_t)(bh * kDk + dV0 + 8) * kSeq + gV1;
  const int ldsK = (wid * 8) * 128;
  const int ldsV = (wid * 16) * 64;

  f32x4 of[8][2];
  const f32x4 z = {0.f, 0.f, 0.f, 0.f};
#pragma unroll
  for (int di = 0; di < 8; ++di) {
    of[di][0] = z;
    of[di][1] = z;
  }
  float m[2] = {-3e38f, -3e38f};
  float l[2] = {0.f, 0.f};

  auto STAGE = [&](int buf, int t) {
    const size_t ko = (size_t)t * 64 * kDModel;
    const size_t vo = (size_t)t * 64;
    bf16_t* dk = sK[buf][0] + ldsK;
    bf16_t* dl = sK[buf][1] + ldsK;
    gload_lds16(pKh0 + ko, dk);
    gload_lds16(pKh1 + ko, dk + 512);
    gload_lds16(pKl0 + ko, dl);
    gload_lds16(pKl1 + ko, dl + 512);
    bf16_t* dv = sV[buf] + ldsV;
    gload_lds16(pV0 + vo, dv);
    gload_lds16(pV1 + vo, dv + 512);
  };

  STAGE(0, 0);
  __syncthreads();

  for (int t = 0; t < nkv; ++t) {
    const int kv0 = t * 64;
    if (t + 1 < nkv) STAGE((t + 1) & 1, t + 1);

    if (kv0 <= qw + 31) {
      const bf16_t* bKh = sK[t & 1][0];
      const bf16_t* bKl = sK[t & 1][1];
      const bf16_t* bV = sV[t & 1];
      const bool maskedw = (kv0 + 63 > qw);

      f32x4 st[4][2];
#pragma unroll
      for (int kt = 0; kt < 4; ++kt) {
        st[kt][0] = z;
        st[kt][1] = z;
      }
#pragma unroll
      for (int kt = 0; kt < 4; ++kt) {
#pragma unroll
        for (int ks = 0; ks < 4; ++ks) {
          const int krow = kt * 16 + lo;
          const int ka = krow * 128 + (((ks * 4 + hi) ^ (krow & 15)) * 8);
          const bf16x8 kh8 = *(const bf16x8*)(bKh + ka);
          const bf16x8 kl8 = *(const bf16x8*)(bKl + ka);
#pragma unroll
          for (int qt = 0; qt < 2; ++qt) {
            st[kt][qt] = mfma32(kh8, qhf[ks][qt], st[kt][qt]);
            st[kt][qt] = mfma32(kh8, qlf[ks][qt], st[kt][qt]);
            st[kt][qt] = mfma32(kl8, qhf[ks][qt], st[kt][qt]);
          }
        }
      }

      bf16x4 pb[4][2];
#pragma unroll
      for (int qt = 0; qt < 2; ++qt) {
        const int q = qw + qt * 16 + lo;
        float mt = -3e38f;
#pragma unroll
        for (int kt = 0; kt < 4; ++kt)
#pragma unroll
          for (int r = 0; r < 4; ++r) {
            float s = st[kt][qt][r];
            if (maskedw && (kv0 + kt * 16 + hi * 4 + r > q)) s = -1e30f;
            st[kt][qt][r] = s;
            mt = fmaxf(mt, s);
          }
        mt = fmaxf(mt, __shfl_xor(mt, 16));
        mt = fmaxf(mt, __shfl_xor(mt, 32));
        if (!__all(mt <= m[qt] + 8.f)) {
          const float mnew = fmaxf(m[qt], mt);
          const float corr = __expf(m[qt] - mnew);
          l[qt] *= corr;
#pragma unroll
          for (int di = 0; di < 8; ++di) of[di][qt] = of[di][qt] * corr;
          m[qt] = mnew;
        }
        float rs = 0.f;
#pragma unroll
        for (int kt = 0; kt < 4; ++kt) {
          bf16x4 pv;
#pragma unroll
          for (int r = 0; r < 4; ++r) {
            const float pp = __expf(st[kt][qt][r] - m[qt]);
            rs += pp;
            pv[r] = (bf16_t)pp;
          }
          pb[kt][qt] = pv;
        }
        rs += __shfl_xor(rs, 16);
        rs += __shfl_xor(rs, 32);
        l[qt] += rs;
      }

#pragma unroll
      for (int di = 0; di < 8; ++di) {
        const int d = di * 16 + lo;
#pragma unroll
        for (int kt = 0; kt < 4; ++kt) {
          const int va =
              d * 64 + (((kt * 2 + (hi >> 1)) ^ (d & 7)) * 8) + (hi & 1) * 4;
          const bf16x4 vf = *(const bf16x4*)(bV + va);
          of[di][0] = mfma16(vf, pb[kt][0], of[di][0]);
          of[di][1] = mfma16(vf, pb[kt][1], of[di][1]);
        }
      }
    }
    __syncthreads();
  }

#pragma unroll
  for (int qt = 0; qt < 2; ++qt) {
    const float linv = 1.f / l[qt];
    const size_t ob =
        (size_t)(b * kSeq + qw + qt * 16 + lo) * kDModel + h * kDk + hi * 4;
#pragma unroll
    for (int di = 0; di < 8; ++di) {
      bf16x4 ov;
#pragma unroll
      for (int r = 0; r < 4; ++r) ov[r] = (bf16_t)(of[di][qt][r] * linv);
      *(bf16x4*)(Ob + ob + di * 16) = ov;
    }
  }
}

}  // namespace

extern "C" void kernel_launch(void* const* d_in, const int* in_sizes, int n_in,
                              void* d_out, int out_size, void* d_ws, size_t ws_size,
                              hipStream_t stream) {
  (void)in_sizes; (void)n_in; (void)out_size;
  const float* x = (const float*)d_in[0];
  const int* tokpos = (const int*)d_in[1];
  const float* wq = (const float*)d_in[2];
  const float* wk = (const float*)d_in[3];
  const float* wv = (const float*)d_in[4];
  const float* wo = (const float*)d_in[5];
  float* out = (float*)d_out;

  char* p = (char*)d_ws;
  auto take = [&](size_t bytes) { char* q = p; p += bytes; return q; };
  float* cost = (float*)take((size_t)kSeq * 64 * sizeof(float));
  float* sint = (float*)take((size_t)kSeq * 64 * sizeof(float));
  const size_t mat = (size_t)kM * kDModel * sizeof(bf16_t);        // 16.8 MB
  const size_t wmat = (size_t)kDModel * kDModel * sizeof(bf16_t);  // 8.4 MB
  bf16_t* xh = (bf16_t*)take(mat);
  bf16_t* xl = (bf16_t*)take(mat);
  bf16_t* wqkth = (bf16_t*)take(2 * wmat);  // rows [0,2048)=wq^T, [2048,4096)=wk^T
  bf16_t* wqktl = (bf16_t*)take(2 * wmat);
  bf16_t* wvt = (bf16_t*)take(wmat);
  bf16_t* wot = (bf16_t*)take(wmat);
  bf16_t* qh = (bf16_t*)take(mat);
  bf16_t* ql = (bf16_t*)take(mat);
  bf16_t* kh = (bf16_t*)take(mat);
  bf16_t* kl = (bf16_t*)take(mat);
  bf16_t* vt = (bf16_t*)take(mat);
  bf16_t* ob = (bf16_t*)take(mat);
  if ((size_t)(p - (char*)d_ws) > ws_size) {
    fprintf(stderr, "MHA: workspace too small: need %zu have %zu\n",
            (size_t)(p - (char*)d_ws), ws_size);
    return;
  }

  k_rope_table<<<dim3(kSeq), dim3(64), 0, stream>>>(cost, sint);
  k_split_x<<<dim3((kM * kDModel) / (256 * 4)), dim3(256), 0, stream>>>(
      x, xh, xl, kM * kDModel);
  {
    dim3 tb(32, 8), tg(kDModel / 32, kDModel / 32);
    k_transpose_w<<<tg, tb, 0, stream>>>(wq, wqkth, wqktl);
    k_transpose_w<<<tg, tb, 0, stream>>>(wk, wqkth + (size_t)2048 * 2048,
                                         wqktl + (size_t)2048 * 2048);
    k_transpose_w<<<tg, tb, 0, stream>>>(wv, wvt, nullptr);
    k_transpose_w<<<tg, tb, 0, stream>>>(wo, wot, nullptr);
  }
  // Fused Q|K projection + RoPE: M=4096, N=4096 (Q|K), K'=3*2048 (192 tiles)
  k_gemmqk2<<<dim3(512), dim3(256), 0, stream>>>(xh, xl, wqkth, wqktl, qh, ql,
                                                 kh, kl, tokpos, cost, sint);
  // V projection -> V^T: M=4096, N=2048, K=2048 (32 tiles)
  k_gemm8<2><<<dim3(256), dim3(512), 0, stream>>>(xh, wvt, vt, 16, 32);
  k_attn4<<<dim3(256), dim3(512), 0, stream>>>(qh, ql, kh, kl, vt, ob);
  // Output projection: fp32 out
  k_gemm8<0><<<dim3(256), dim3(512), 0, stream>>>(ob, wot, out, 16, 32);
}

// Round 10
// 421.463 us; speedup vs baseline: 1.4716x; 1.4716x over previous
//
#include <hip/hip_runtime.h>
#include <hip/hip_bf16.h>
#include <cstdio>

namespace {

constexpr int kSeq = 2048;
constexpr int kDModel = 2048;
constexpr int kHeads = 16;
constexpr int kDk = 128;
constexpr int kBatch = 2;
constexpr int kM = kBatch * kSeq;  // 4096 rows of x
constexpr float kQScale = 0.08838834764831845f;  // 1/sqrt(128)

typedef __bf16 bf16_t;
typedef __bf16 bf16x8 __attribute__((ext_vector_type(8)));
typedef __bf16 bf16x4 __attribute__((ext_vector_type(4)));
typedef float f32x4 __attribute__((ext_vector_type(4)));
typedef short s16x4 __attribute__((ext_vector_type(4)));

__device__ __forceinline__ f32x4 mfma32(bf16x8 a, bf16x8 b, f32x4 c) {
  return __builtin_amdgcn_mfma_f32_16x16x32_bf16(a, b, c, 0, 0, 0);
}

#if __has_builtin(__builtin_amdgcn_mfma_f32_16x16x16_bf16)
__device__ __forceinline__ f32x4 mfma16(bf16x4 a, bf16x4 b, f32x4 c) {
  return __builtin_amdgcn_mfma_f32_16x16x16_bf16(a, b, c, 0, 0, 0);
}
#else
__device__ __forceinline__ f32x4 mfma16(bf16x4 a, bf16x4 b, f32x4 c) {
  union U { bf16x4 b; s16x4 s; } ua, ub;
  ua.b = a; ub.b = b;
  return __builtin_amdgcn_mfma_f32_16x16x16bf16_1k(ua.s, ub.s, c, 0, 0, 0);
}
#endif

using gas_void = const __attribute__((address_space(1))) void;
using las_void = __attribute__((address_space(3))) void;

__device__ __forceinline__ void gload_lds16(const bf16_t* g, bf16_t* l) {
  __builtin_amdgcn_global_load_lds((gas_void*)g, (las_void*)l, 16, 0, 0);
}

// ---------------- RoPE table (fp64 for max fidelity vs np reference) --------
__global__ void k_rope_table(float* __restrict__ cost, float* __restrict__ sint) {
  const int p = blockIdx.x;
  const int i = threadIdx.x;
  const double inv = exp(-(double)(2 * i) * 9.210340371976184 / 128.0);
  const double ang = (double)p * inv;
  cost[p * 64 + i] = (float)cos(ang);
  sint[p * 64 + i] = (float)sin(ang);
}

// ---------------- x -> (hi,lo) bf16 split -----------------------------------
__global__ void k_split_x(const float* __restrict__ x, bf16_t* __restrict__ xh,
                          bf16_t* __restrict__ xl, int n) {
  const int idx = (blockIdx.x * blockDim.x + threadIdx.x) * 4;
  if (idx >= n) return;
  const float4 v = *(const float4*)(x + idx);
  const float vv[4] = {v.x, v.y, v.z, v.w};
  bf16x4 hv, lv;
#pragma unroll
  for (int j = 0; j < 4; ++j) {
    const bf16_t h = (bf16_t)vv[j];
    hv[j] = h;
    lv[j] = (bf16_t)(vv[j] - (float)h);
  }
  *(bf16x4*)(xh + idx) = hv;
  *(bf16x4*)(xl + idx) = lv;
}

// ---------------- W (fp32 [K][N]) -> W^T bf16 hi(/lo) [N][K] ----------------
__global__ void k_transpose_w(const float* __restrict__ w, bf16_t* __restrict__ wth,
                              bf16_t* __restrict__ wtl) {
  __shared__ float tile[32][33];
  const int bx = blockIdx.x * 32;  // n
  const int by = blockIdx.y * 32;  // k
  const int tx = threadIdx.x, ty = threadIdx.y;
#pragma unroll
  for (int i = 0; i < 32; i += 8)
    tile[ty + i][tx] = w[(size_t)(by + ty + i) * kDModel + bx + tx];
  __syncthreads();
#pragma unroll
  for (int i = 0; i < 32; i += 8) {
    const float v = tile[tx][ty + i];
    const size_t o = (size_t)(bx + ty + i) * kDModel + by + tx;
    const bf16_t h = (bf16_t)v;
    wth[o] = h;
    if (wtl) wtl[o] = (bf16_t)(v - (float)h);
  }
}

// ---------------- Fused Q|K projection: fine-phase (m201 quantum) -----------
// BM=BN=256, BK=32, 8 waves (2M x 4N), wave-tile 128x64 (acc[8][4]).
// Per K-tile/wave: 32 MFMA, 12 ds_read_b128 (0.375 ratio). LDS ring-3 of
// 32KB slots (A 16K + B 16K) = 96KB. Per K-tile TWO phases, each exactly
// {ds-reads, stage 2 gload, barrier, lgkm(0), 16 MFMA, barrier} — m201's
// 16-MFMA quantum with lgkm AFTER the barrier; vmcnt(4) once per tile
// (tile t+2's 4 loads stay in flight; no mid-loop drain).
// Ledger: group t stages tile t+2 into slot (t+2)%3 (last read ended at
// group t-1's final barrier -> WAR-safe at issue time); group-t vmcnt(4)
// confirms tile t+1 before group t+1 reads it (RAW-safe). Tail: t==ntk-2
// uses vmcnt(0). Prologue: stage t0,t1; vmcnt(4) confirms t0.
// Swizzle (64B rows, 4 chunks): pos = chunk ^ ((row>>1)&3), both sides
// (r8-verified: 0 bank conflicts).
// Segmented K' = [Ah,Ah,Al] x [Bh,Bl,Bh] (split-bf16 ~fp32), 192 tiles.
__global__ __launch_bounds__(512) void k_gemmf(
    const bf16_t* __restrict__ Ah, const bf16_t* __restrict__ Al,
    const bf16_t* __restrict__ Bh, const bf16_t* __restrict__ Bl,
    bf16_t* __restrict__ Qh, bf16_t* __restrict__ Ql,
    bf16_t* __restrict__ Kh, bf16_t* __restrict__ Kl,
    const int* __restrict__ tokpos, const float* __restrict__ cost,
    const float* __restrict__ sint) {
  __shared__ __align__(16) bf16_t sA[3][256 * 32];
  __shared__ __align__(16) bf16_t sB[3][256 * 32];
  constexpr int ntk = 192;

  const int tid = threadIdx.x;
  const int wid = tid >> 6, lane = tid & 63;
  const int lo = lane & 15, hi = lane >> 4;
  const int wr = wid >> 2;  // 0..1  (M half)
  const int wc = wid & 3;   // 0..3  (N quarter)

  const int bid = blockIdx.x;  // 256 blocks, 1/CU
  const int wgid = (bid & 7) * 32 + (bid >> 3);  // bijective XCD swizzle
  const int m0 = (wgid >> 4) * 256, n0 = (wgid & 15) * 256;

  // ---- staging source constants (pre-swizzled: chunk ^ ((row>>1)&3)) ----
  const int sr = tid >> 2;                           // row 0..127 per issue
  const int sc = ((tid & 3) ^ ((tid >> 3) & 3)) * 8; // swizzled chunk (elems)
  size_t offA[2], offB[2];
#pragma unroll
  for (int i = 0; i < 2; ++i) {
    offA[i] = (size_t)(m0 + i * 128 + sr) * 2048 + sc;
    offB[i] = (size_t)(n0 + i * 128 + sr) * 2048 + sc;
  }

  auto STAGE_A = [&](int slot, int tt) {
    const bf16_t* As = (tt < 128) ? Ah : Al;
    const int kb = (tt & 63) * 32;
#pragma unroll
    for (int i = 0; i < 2; ++i)
      gload_lds16(As + offA[i] + kb, sA[slot] + i * 4096 + tid * 8);
  };
  auto STAGE_B = [&](int slot, int tt) {
    const bf16_t* Bs = (tt < 64) ? Bh : ((tt < 128) ? Bl : Bh);
    const int kb = (tt & 63) * 32;
#pragma unroll
    for (int i = 0; i < 2; ++i)
      gload_lds16(Bs + offB[i] + kb, sB[slot] + i * 4096 + tid * 8);
  };

  // ---- fragment LDS offsets (row*32 + swizzled chunk*8) ----
  const int xq = (lo >> 1) & 3;  // == (row>>1)&3 for row = 16k + lo
  int aoff[8], boff[4];
#pragma unroll
  for (int mi = 0; mi < 8; ++mi)
    aoff[mi] = (wr * 128 + mi * 16 + lo) * 32 + ((hi ^ xq) * 8);
#pragma unroll
  for (int ni = 0; ni < 4; ++ni)
    boff[ni] = (wc * 64 + ni * 16 + lo) * 32 + ((hi ^ xq) * 8);

  f32x4 acc[8][4];
  const f32x4 z = {0.f, 0.f, 0.f, 0.f};
#pragma unroll
  for (int i = 0; i < 8; ++i)
#pragma unroll
    for (int j = 0; j < 4; ++j) acc[i][j] = z;

  // ---- prologue: stage tiles 0,1; confirm tile 0 (tile 1's 4 in flight) ----
  STAGE_A(0, 0);
  STAGE_B(0, 0);
  STAGE_A(1, 1);
  STAGE_B(1, 1);
  asm volatile("s_waitcnt vmcnt(4)" ::: "memory");
  __builtin_amdgcn_s_barrier();
  __builtin_amdgcn_sched_barrier(0);

  int s0 = 0;
#pragma unroll 1
  for (int t = 0; t < ntk; ++t) {
    const bf16_t* sa = sA[s0];
    const bf16_t* sb = sB[s0];
    int s2 = s0 + 2;
    if (s2 >= 3) s2 -= 3;
    const bool pf = (t + 2 < ntk);

    // ---- phase 0: reads a0-3 + b0-3; stage A(t+2); 16 MFMA ----
    bf16x8 a[4], b[4];
#pragma unroll
    for (int mi = 0; mi < 4; ++mi) a[mi] = *(const bf16x8*)(sa + aoff[mi]);
#pragma unroll
    for (int ni = 0; ni < 4; ++ni) b[ni] = *(const bf16x8*)(sb + boff[ni]);
    if (pf) STAGE_A(s2, t + 2);
    __builtin_amdgcn_sched_barrier(0);
    __builtin_amdgcn_s_barrier();
    asm volatile("s_waitcnt lgkmcnt(0)" ::: "memory");
    __builtin_amdgcn_sched_barrier(0);
    __builtin_amdgcn_s_setprio(1);
#pragma unroll
    for (int ni = 0; ni < 4; ++ni)
#pragma unroll
      for (int mi = 0; mi < 4; ++mi)
        acc[mi][ni] = mfma32(a[mi], b[ni], acc[mi][ni]);
    __builtin_amdgcn_s_setprio(0);
    __builtin_amdgcn_sched_barrier(0);
    __builtin_amdgcn_s_barrier();
    __builtin_amdgcn_sched_barrier(0);

    // ---- phase 1: reads a4-7; stage B(t+2); group-end vmcnt; 16 MFMA ----
    bf16x8 a2[4];
#pragma unroll
    for (int mi = 0; mi < 4; ++mi) a2[mi] = *(const bf16x8*)(sa + aoff[4 + mi]);
    if (pf) STAGE_B(s2, t + 2);
    __builtin_amdgcn_sched_barrier(0);
    if (pf)
      asm volatile("s_waitcnt vmcnt(4)" ::: "memory");
    else if (t == ntk - 2)
      asm volatile("s_waitcnt vmcnt(0)" ::: "memory");
    __builtin_amdgcn_s_barrier();
    asm volatile("s_waitcnt lgkmcnt(0)" ::: "memory");
    __builtin_amdgcn_sched_barrier(0);
    __builtin_amdgcn_s_setprio(1);
#pragma unroll
    for (int ni = 0; ni < 4; ++ni)
#pragma unroll
      for (int mi = 0; mi < 4; ++mi)
        acc[4 + mi][ni] = mfma32(a2[mi], b[ni], acc[4 + mi][ni]);
    __builtin_amdgcn_s_setprio(0);
    __builtin_amdgcn_sched_barrier(0);
    __builtin_amdgcn_s_barrier();
    __builtin_amdgcn_sched_barrier(0);

    s0 += 1;
    if (s0 >= 3) s0 = 0;
  }

  // ---- epilogue: RoPE + split-bf16 store; block-uniform Q/K select ----
  const int qk = n0 >> 11;  // 0 = Q (cols<2048), 1 = K
  bf16_t* Xh = qk ? Kh : Qh;
  bf16_t* Xl = qk ? Kl : Ql;
  const float scale = qk ? 1.0f : kQScale;
  const int is64 = (tokpos[1] == 0) ? 1 : 0;
#pragma unroll
  for (int mi = 0; mi < 8; ++mi) {
#pragma unroll
    for (int r = 0; r < 4; ++r) {
      const int row = m0 + wr * 128 + mi * 16 + hi * 4 + r;
      const int pos = is64 ? tokpos[2 * row] : tokpos[row];
#pragma unroll
      for (int ni = 0; ni < 4; ++ni) {
        const int col = n0 + wc * 64 + ni * 16 + lo;
        const float v = acc[mi][ni][r] * scale;
        const float pv = __shfl_xor(v, 1);  // paired column (col^1)
        const int ip = (col & 127) >> 1;
        const float c = cost[pos * 64 + ip];
        const float sn = sint[pos * 64 + ip];
        const float sgn = (lo & 1) ? sn : -sn;
        const float rv = v * c + pv * sgn;
        const bf16_t hb = (bf16_t)rv;
        const size_t o = (size_t)row * 2048 + (col & 2047);
        Xh[o] = hb;
        Xl[o] = (bf16_t)(rv - (float)hb);
      }
    }
  }
}

// ---------------- Ring-3 counted-vmcnt MFMA GEMM (V / O projections) --------
// BM=256, BN=128, BK=64. 8 waves (4Mx2N), wave C = 64x64 (acc[4][4]).
// EPI: 0 = fp32 store; 2 = bf16 V^T store [bh*128+d][s].
template <int EPI>
__global__ __launch_bounds__(512) void k_gemm8(
    const bf16_t* __restrict__ Ah, const bf16_t* __restrict__ Bh,
    void* __restrict__ O0, int NT, int ntk) {
  __shared__ __align__(16) bf16_t sA[3][256 * 64];
  __shared__ __align__(16) bf16_t sB[3][128 * 64];

  const int tid = threadIdx.x;
  const int wid = tid >> 6, lane = tid & 63;
  const int lo = lane & 15, hi = lane >> 4;
  const int wrr = wid >> 1, wcc = wid & 1;
  const int x7 = lo & 7;

  const int bid = blockIdx.x;
  const int wgid = (bid & 7) * (gridDim.x >> 3) + (bid >> 3);
  const int mt = wgid / NT, nt = wgid % NT;
  const int m0 = mt * 256, n0 = nt * 128;

  const int rB = tid >> 3;
  const int ch8 = ((tid & 7) ^ (rB & 7)) * 8;
  size_t offA[4], offB[2];
#pragma unroll
  for (int u = 0; u < 2; ++u)
#pragma unroll
    for (int i = 0; i < 2; ++i)
      offA[u * 2 + i] = (size_t)(m0 + u * 128 + i * 64 + rB) * 2048 + ch8;
#pragma unroll
  for (int i = 0; i < 2; ++i)
    offB[i] = (size_t)(n0 + i * 64 + rB) * 2048 + ch8;
  const int ldsOff = wid * 512;

  auto STAGE_A = [&](int slot, int t) {
    const bf16_t* base = Ah + t * 64;
    bf16_t* d = sA[slot] + ldsOff;
#pragma unroll
    for (int ui = 0; ui < 4; ++ui) gload_lds16(base + offA[ui], d + ui * 4096);
  };
  auto STAGE_B = [&](int slot, int t) {
    const bf16_t* base = Bh + t * 64;
    bf16_t* d = sB[slot] + ldsOff;
#pragma unroll
    for (int i = 0; i < 2; ++i) gload_lds16(base + offB[i], d + i * 4096);
  };

  int aoff[4][2], boff[4][2];
#pragma unroll
  for (int mi = 0; mi < 4; ++mi)
#pragma unroll
    for (int ks = 0; ks < 2; ++ks)
      aoff[mi][ks] = (wrr * 64 + mi * 16 + lo) * 64 + (((ks * 4 + hi) ^ x7) * 8);
#pragma unroll
  for (int ni = 0; ni < 4; ++ni)
#pragma unroll
    for (int ks = 0; ks < 2; ++ks)
      boff[ni][ks] = (wcc * 64 + ni * 16 + lo) * 64 + (((ks * 4 + hi) ^ x7) * 8);

  f32x4 acc[4][4];
  const f32x4 z = {0.f, 0.f, 0.f, 0.f};
#pragma unroll
  for (int i = 0; i < 4; ++i)
#pragma unroll
    for (int j = 0; j < 4; ++j) acc[i][j] = z;

  STAGE_A(0, 0);
  STAGE_B(0, 0);
  STAGE_A(1, 1);
  STAGE_B(1, 1);
  asm volatile("s_waitcnt vmcnt(6)" ::: "memory");
  __builtin_amdgcn_s_barrier();
  asm volatile("" ::: "memory");

  int s0 = 0;
  for (int t = 0; t < ntk; ++t) {
    const bf16_t* sa = sA[s0];
    const bf16_t* sb = sB[s0];
    int s2 = s0 + 2;
    if (s2 >= 3) s2 -= 3;
    const bool pf = (t + 2 < ntk);

    bf16x8 af[2][2], bfr[4][2];
#pragma unroll
    for (int mi = 0; mi < 2; ++mi)
#pragma unroll
      for (int ks = 0; ks < 2; ++ks)
        af[mi][ks] = *(const bf16x8*)(sa + aoff[mi][ks]);
#pragma unroll
    for (int ni = 0; ni < 4; ++ni)
#pragma unroll
      for (int ks = 0; ks < 2; ++ks)
        bfr[ni][ks] = *(const bf16x8*)(sb + boff[ni][ks]);
    if (pf) STAGE_A(s2, t + 2);
    asm volatile("" ::: "memory");
    __builtin_amdgcn_s_barrier();
    asm volatile("" ::: "memory");
    __builtin_amdgcn_s_setprio(1);
#pragma unroll
    for (int ni = 0; ni < 4; ++ni)
#pragma unroll
      for (int mi = 0; mi < 2; ++mi)
#pragma unroll
        for (int ks = 0; ks < 2; ++ks)
          acc[mi][ni] = mfma32(af[mi][ks], bfr[ni][ks], acc[mi][ni]);
    __builtin_amdgcn_s_setprio(0);

    bf16x8 ag[2][2];
#pragma unroll
    for (int mi = 0; mi < 2; ++mi)
#pragma unroll
      for (int ks = 0; ks < 2; ++ks)
        ag[mi][ks] = *(const bf16x8*)(sa + aoff[2 + mi][ks]);
    if (pf) STAGE_B(s2, t + 2);
    if (pf)
      asm volatile("s_waitcnt vmcnt(6)" ::: "memory");
    else
      asm volatile("s_waitcnt vmcnt(0)" ::: "memory");
    __builtin_amdgcn_s_barrier();
    asm volatile("" ::: "memory");
    __builtin_amdgcn_s_setprio(1);
#pragma unroll
    for (int ni = 0; ni < 4; ++ni)
#pragma unroll
      for (int mi = 0; mi < 2; ++mi)
#pragma unroll
        for (int ks = 0; ks < 2; ++ks)
          acc[2 + mi][ni] = mfma32(ag[mi][ks], bfr[ni][ks], acc[2 + mi][ni]);
    __builtin_amdgcn_s_setprio(0);

    s0 += 1;
    if (s0 >= 3) s0 = 0;
  }

  if constexpr (EPI == 0) {
    float* C = (float*)O0;
#pragma unroll
    for (int mi = 0; mi < 4; ++mi)
#pragma unroll
      for (int ni = 0; ni < 4; ++ni)
#pragma unroll
        for (int r = 0; r < 4; ++r) {
          const int row = m0 + wrr * 64 + mi * 16 + hi * 4 + r;
          const int col = n0 + wcc * 64 + ni * 16 + lo;
          C[(size_t)row * 2048 + col] = acc[mi][ni][r];
        }
  } else {  // EPI == 2 : V^T per head [bh*128+d][s]
    bf16_t* VT = (bf16_t*)O0;
#pragma unroll
    for (int mi = 0; mi < 4; ++mi)
#pragma unroll
      for (int ni = 0; ni < 4; ++ni) {
        const int col = n0 + wcc * 64 + ni * 16 + lo;
        const int h = col >> 7, d = col & 127;
        const int rowb = m0 + wrr * 64 + mi * 16 + hi * 4;
        const int b = rowb >> 11, s = rowb & (kSeq - 1);
        bf16x4 ov;
#pragma unroll
        for (int r = 0; r < 4; ++r) ov[r] = (bf16_t)acc[mi][ni][r];
        *(bf16x4*)(VT + ((size_t)((b * kHeads + h) * kDk + d)) * kSeq + s) = ov;
      }
  }
}

// ---------------- Causal flash attention, strip-paired, 8 waves -------------
__global__ __launch_bounds__(512, 2) void k_attn4(
    const bf16_t* __restrict__ Qh, const bf16_t* __restrict__ Ql,
    const bf16_t* __restrict__ Kh, const bf16_t* __restrict__ Kl,
    const bf16_t* __restrict__ VT, bf16_t* __restrict__ Ob) {
  __shared__ __align__(16) bf16_t sK[2][2][64 * 128];
  __shared__ __align__(16) bf16_t sV[2][128 * 64];

  const int tid = threadIdx.x;
  const int wid = tid >> 6, lane = tid & 63;
  const int lo = lane & 15, hi = lane >> 4;
  const int flat = blockIdx.x;  // 256 blocks
  const int j = flat >> 3;
  const int bh = (flat & 7) * 4 + (j & 3);  // XCD x -> heads 4x..4x+3
  const int p = j >> 2;                     // 0..7
  const int b = bh >> 4, h = bh & 15;
  const int qiW = (wid < 4) ? (15 - p) : p;
  const int qw = qiW * 128 + (wid & 3) * 32;
  const int nkv = 2 * (15 - p) + 2;

  bf16x8 qhf[4][2], qlf[4][2];
  {
    const size_t qbase =
        (size_t)(b * kSeq + qw + lo) * kDModel + h * kDk + hi * 8;
#pragma unroll
    for (int qt = 0; qt < 2; ++qt)
#pragma unroll
      for (int ks = 0; ks < 4; ++ks) {
        const size_t o = qbase + (size_t)qt * 16 * kDModel + ks * 32;
        qhf[ks][qt] = *(const bf16x8*)(Qh + o);
        qlf[ks][qt] = *(const bf16x8*)(Ql + o);
      }
  }

  const int rK0 = wid * 8 + (lane >> 4);
  const int gK0 = ((lane & 15) ^ (rK0 & 15)) * 8;
  const int gK1 = ((lane & 15) ^ ((rK0 + 4) & 15)) * 8;
  const bf16_t* pKh0 = Kh + (size_t)(b * kSeq + rK0) * kDModel + h * kDk + gK0;
  const bf16_t* pKh1 = Kh + (size_t)(b * kSeq + rK0 + 4) * kDModel + h * kDk + gK1;
  const bf16_t* pKl0 = Kl + (pKh0 - Kh);
  const bf16_t* pKl1 = Kl + (pKh1 - Kh);
  const int dV0 = wid * 16 + (lane >> 3);
  const int gV0 = ((lane & 7) ^ (dV0 & 7)) * 8;
  const int gV1 = ((lane & 7) ^ ((dV0 + 8) & 7)) * 8;
  const bf16_t* pV0 = VT + (size_t)(bh * kDk + dV0) * kSeq + gV0;
  const bf16_t* pV1 = VT + (size_t)(bh * kDk + dV0 + 8) * kSeq + gV1;
  const int ldsK = (wid * 8) * 128;
  const int ldsV = (wid * 16) * 64;

  f32x4 of[8][2];
  const f32x4 z = {0.f, 0.f, 0.f, 0.f};
#pragma unroll
  for (int di = 0; di < 8; ++di) {
    of[di][0] = z;
    of[di][1] = z;
  }
  float m[2] = {-3e38f, -3e38f};
  float l[2] = {0.f, 0.f};

  auto STAGE = [&](int buf, int t) {
    const size_t ko = (size_t)t * 64 * kDModel;
    const size_t vo = (size_t)t * 64;
    bf16_t* dk = sK[buf][0] + ldsK;
    bf16_t* dl = sK[buf][1] + ldsK;
    gload_lds16(pKh0 + ko, dk);
    gload_lds16(pKh1 + ko, dk + 512);
    gload_lds16(pKl0 + ko, dl);
    gload_lds16(pKl1 + ko, dl + 512);
    bf16_t* dv = sV[buf] + ldsV;
    gload_lds16(pV0 + vo, dv);
    gload_lds16(pV1 + vo, dv + 512);
  };

  STAGE(0, 0);
  __syncthreads();

  for (int t = 0; t < nkv; ++t) {
    const int kv0 = t * 64;
    if (t + 1 < nkv) STAGE((t + 1) & 1, t + 1);

    if (kv0 <= qw + 31) {
      const bf16_t* bKh = sK[t & 1][0];
      const bf16_t* bKl = sK[t & 1][1];
      const bf16_t* bV = sV[t & 1];
      const bool maskedw = (kv0 + 63 > qw);

      f32x4 st[4][2];
#pragma unroll
      for (int kt = 0; kt < 4; ++kt) {
        st[kt][0] = z;
        st[kt][1] = z;
      }
#pragma unroll
      for (int kt = 0; kt < 4; ++kt) {
#pragma unroll
        for (int ks = 0; ks < 4; ++ks) {
          const int krow = kt * 16 + lo;
          const int ka = krow * 128 + (((ks * 4 + hi) ^ (krow & 15)) * 8);
          const bf16x8 kh8 = *(const bf16x8*)(bKh + ka);
          const bf16x8 kl8 = *(const bf16x8*)(bKl + ka);
#pragma unroll
          for (int qt = 0; qt < 2; ++qt) {
            st[kt][qt] = mfma32(kh8, qhf[ks][qt], st[kt][qt]);
            st[kt][qt] = mfma32(kh8, qlf[ks][qt], st[kt][qt]);
            st[kt][qt] = mfma32(kl8, qhf[ks][qt], st[kt][qt]);
          }
        }
      }

      bf16x4 pb[4][2];
#pragma unroll
      for (int qt = 0; qt < 2; ++qt) {
        const int q = qw + qt * 16 + lo;
        float mt = -3e38f;
#pragma unroll
        for (int kt = 0; kt < 4; ++kt)
#pragma unroll
          for (int r = 0; r < 4; ++r) {
            float s = st[kt][qt][r];
            if (maskedw && (kv0 + kt * 16 + hi * 4 + r > q)) s = -1e30f;
            st[kt][qt][r] = s;
            mt = fmaxf(mt, s);
          }
        mt = fmaxf(mt, __shfl_xor(mt, 16));
        mt = fmaxf(mt, __shfl_xor(mt, 32));
        if (!__all(mt <= m[qt] + 8.f)) {
          const float mnew = fmaxf(m[qt], mt);
          const float corr = __expf(m[qt] - mnew);
          l[qt] *= corr;
#pragma unroll
          for (int di = 0; di < 8; ++di) of[di][qt] = of[di][qt] * corr;
          m[qt] = mnew;
        }
        float rs = 0.f;
#pragma unroll
        for (int kt = 0; kt < 4; ++kt) {
          bf16x4 pv;
#pragma unroll
          for (int r = 0; r < 4; ++r) {
            const float pp = __expf(st[kt][qt][r] - m[qt]);
            rs += pp;
            pv[r] = (bf16_t)pp;
          }
          pb[kt][qt] = pv;
        }
        rs += __shfl_xor(rs, 16);
        rs += __shfl_xor(rs, 32);
        l[qt] += rs;
      }

#pragma unroll
      for (int di = 0; di < 8; ++di) {
        const int d = di * 16 + lo;
#pragma unroll
        for (int kt = 0; kt < 4; ++kt) {
          const int va =
              d * 64 + (((kt * 2 + (hi >> 1)) ^ (d & 7)) * 8) + (hi & 1) * 4;
          const bf16x4 vf = *(const bf16x4*)(bV + va);
          of[di][0] = mfma16(vf, pb[kt][0], of[di][0]);
          of[di][1] = mfma16(vf, pb[kt][1], of[di][1]);
        }
      }
    }
    __syncthreads();
  }

#pragma unroll
  for (int qt = 0; qt < 2; ++qt) {
    const float linv = 1.f / l[qt];
    const size_t ob =
        (size_t)(b * kSeq + qw + qt * 16 + lo) * kDModel + h * kDk + hi * 4;
#pragma unroll
    for (int di = 0; di < 8; ++di) {
      bf16x4 ov;
#pragma unroll
      for (int r = 0; r < 4; ++r) ov[r] = (bf16_t)(of[di][qt][r] * linv);
      *(bf16x4*)(Ob + ob + di * 16) = ov;
    }
  }
}

}  // namespace

extern "C" void kernel_launch(void* const* d_in, const int* in_sizes, int n_in,
                              void* d_out, int out_size, void* d_ws, size_t ws_size,
                              hipStream_t stream) {
  (void)in_sizes; (void)n_in; (void)out_size;
  const float* x = (const float*)d_in[0];
  const int* tokpos = (const int*)d_in[1];
  const float* wq = (const float*)d_in[2];
  const float* wk = (const float*)d_in[3];
  const float* wv = (const float*)d_in[4];
  const float* wo = (const float*)d_in[5];
  float* out = (float*)d_out;

  char* p = (char*)d_ws;
  auto take = [&](size_t bytes) { char* q = p; p += bytes; return q; };
  float* cost = (float*)take((size_t)kSeq * 64 * sizeof(float));
  float* sint = (float*)take((size_t)kSeq * 64 * sizeof(float));
  const size_t mat = (size_t)kM * kDModel * sizeof(bf16_t);        // 16.8 MB
  const size_t wmat = (size_t)kDModel * kDModel * sizeof(bf16_t);  // 8.4 MB
  bf16_t* xh = (bf16_t*)take(mat);
  bf16_t* xl = (bf16_t*)take(mat);
  bf16_t* wqkth = (bf16_t*)take(2 * wmat);  // rows [0,2048)=wq^T, [2048,4096)=wk^T
  bf16_t* wqktl = (bf16_t*)take(2 * wmat);
  bf16_t* wvt = (bf16_t*)take(wmat);
  bf16_t* wot = (bf16_t*)take(wmat);
  bf16_t* qh = (bf16_t*)take(mat);
  bf16_t* ql = (bf16_t*)take(mat);
  bf16_t* kh = (bf16_t*)take(mat);
  bf16_t* kl = (bf16_t*)take(mat);
  bf16_t* vt = (bf16_t*)take(mat);
  bf16_t* ob = (bf16_t*)take(mat);
  if ((size_t)(p - (char*)d_ws) > ws_size) {
    fprintf(stderr, "MHA: workspace too small: need %zu have %zu\n",
            (size_t)(p - (char*)d_ws), ws_size);
    return;
  }

  k_rope_table<<<dim3(kSeq), dim3(64), 0, stream>>>(cost, sint);
  k_split_x<<<dim3((kM * kDModel) / (256 * 4)), dim3(256), 0, stream>>>(
      x, xh, xl, kM * kDModel);
  {
    dim3 tb(32, 8), tg(kDModel / 32, kDModel / 32);
    k_transpose_w<<<tg, tb, 0, stream>>>(wq, wqkth, wqktl);
    k_transpose_w<<<tg, tb, 0, stream>>>(wk, wqkth + (size_t)2048 * 2048,
                                         wqktl + (size_t)2048 * 2048);
    k_transpose_w<<<tg, tb, 0, stream>>>(wv, wvt, nullptr);
    k_transpose_w<<<tg, tb, 0, stream>>>(wo, wot, nullptr);
  }
  // Fused Q|K projection + RoPE: M=4096, N=4096 (Q|K), K'=3*2048 (192 tiles)
  k_gemmf<<<dim3(256), dim3(512), 0, stream>>>(xh, xl, wqkth, wqktl, qh, ql,
                                               kh, kl, tokpos, cost, sint);
  // V projection -> V^T: M=4096, N=2048, K=2048 (32 tiles)
  k_gemm8<2><<<dim3(256), dim3(512), 0, stream>>>(xh, wvt, vt, 16, 32);
  k_attn4<<<dim3(256), dim3(512), 0, stream>>>(qh, ql, kh, kl, vt, ob);
  // Output projection: fp32 out
  k_gemm8<0><<<dim3(256), dim3(512), 0, stream>>>(ob, wot, out, 16, 32);
}